// Round 1
// 1236.490 us; speedup vs baseline: 1.0283x; 1.0283x over previous
//
#include <hip/hip_runtime.h>

#define N_BINS 15
#define BLOCKS 1024

typedef float f4 __attribute__((ext_vector_type(4)));

__device__ __forceinline__ float max4(f4 v) {
    return fmaxf(fmaxf(v[0], v[1]), fmaxf(v[2], v[3]));
}

// d_ws layout (floats): [0..14]=count, [15..29]=conf_sum, [30..44]=acc_sum
__global__ __launch_bounds__(256) void ece_main(
    const float* __restrict__ probs,
    const int* __restrict__ labels,
    const int* __restrict__ is_logit_p,
    float* __restrict__ bins,
    int n_rows)
{
    // per-wave partial bins: wave -> component(count,conf,acc) -> bin (padded 17)
    __shared__ float s_bins[4][3][17];

    const int tid = threadIdx.x;
    if (tid < 4 * 3 * 17) ((float*)s_bins)[tid] = 0.f;
    __syncthreads();

    const int is_logit = *is_logit_p;   // wave-uniform
    const int lane = tid & 63;
    const int wave = tid >> 6;          // 0..3
    const int sub  = tid & 7;           // lane within 8-lane row group
    const int grp  = tid >> 3;          // row group within block: 0..31

    long long row = (long long)blockIdx.x * 32 + grp;
    const long long stride = (long long)gridDim.x * 32;
    const size_t pstep = (size_t)stride * 32;   // float4 units per grid-stride step

    const f4* rp = (const f4*)probs + (size_t)row * 32 + sub;

    // ---- prologue: prefetch iteration 0 ----
    f4 a0, a1, a2, a3;
    int lab = 0;
    bool valid = row < n_rows;
    if (valid) {
        a0 = __builtin_nontemporal_load(rp);
        a1 = __builtin_nontemporal_load(rp + 8);
        a2 = __builtin_nontemporal_load(rp + 16);
        a3 = __builtin_nontemporal_load(rp + 24);
        lab = labels[row];
    }

    while (valid) {
        // ---- issue next iteration's loads before touching current data ----
        const long long nrow = row + stride;
        const bool nvalid = nrow < n_rows;
        const f4* np = rp + pstep;
        f4 b0, b1, b2, b3;
        int nlab = 0;
        if (nvalid) {
            b0 = __builtin_nontemporal_load(np);
            b1 = __builtin_nontemporal_load(np + 8);
            b2 = __builtin_nontemporal_load(np + 16);
            b3 = __builtin_nontemporal_load(np + 24);
            nlab = labels[nrow];
        }

        // ---- local max over 16 elements (tree) ----
        float m = fmaxf(fmaxf(max4(a0), max4(a1)), fmaxf(max4(a2), max4(a3)));
        // ---- group max: 3 xor-shuffles within the 8-lane group ----
        m = fmaxf(m, __shfl_xor(m, 1, 64));
        m = fmaxf(m, __shfl_xor(m, 2, 64));
        m = fmaxf(m, __shfl_xor(m, 4, 64));

        // ---- confidence ----
        float conf;
        if (is_logit) {
            float e0 = (__expf(a0[0] - m) + __expf(a0[1] - m))
                     + (__expf(a0[2] - m) + __expf(a0[3] - m));
            float e1 = (__expf(a1[0] - m) + __expf(a1[1] - m))
                     + (__expf(a1[2] - m) + __expf(a1[3] - m));
            float e2 = (__expf(a2[0] - m) + __expf(a2[1] - m))
                     + (__expf(a2[2] - m) + __expf(a2[3] - m));
            float e3 = (__expf(a3[0] - m) + __expf(a3[1] - m))
                     + (__expf(a3[2] - m) + __expf(a3[3] - m));
            float s = (e0 + e1) + (e2 + e3);
            s += __shfl_xor(s, 1, 64);
            s += __shfl_xor(s, 2, 64);
            s += __shfl_xor(s, 4, 64);
            conf = 1.0f / s;            // max softmax prob = 1 / sum(exp(x-m))
        } else {
            conf = m;
        }

        // ---- accuracy: does the label position hold the row max? ----
        const int f = lab >> 2;         // float4 index of label
        const int c = lab & 3;          // component
        const int k = f >> 3;           // which of a0..a3
        f4 vk = (k == 0) ? a0 : (k == 1) ? a1 : (k == 2) ? a2 : a3;
        float lv = (c == 0) ? vk[0] : (c == 1) ? vk[1] : (c == 2) ? vk[2] : vk[3];
        const bool mine = ((f & 7) == sub) && (lv == m);
        const unsigned long long bal = __ballot(mine);

        if (sub == 0) {
            int bin = (int)ceilf(conf * (float)N_BINS) - 1;
            bin = bin < 0 ? 0 : (bin > N_BINS - 1 ? N_BINS - 1 : bin);
            const float acc = ((bal >> (lane & 56)) & 0xFFull) ? 1.0f : 0.0f;
            atomicAdd(&s_bins[wave][0][bin], 1.0f);
            atomicAdd(&s_bins[wave][1][bin], conf);
            atomicAdd(&s_bins[wave][2][bin], acc);
        }

        // ---- rotate the pipeline ----
        row = nrow; valid = nvalid; rp = np;
        a0 = b0; a1 = b1; a2 = b2; a3 = b3; lab = nlab;
    }

    __syncthreads();
    if (tid < 3 * N_BINS) {
        const int c = tid / N_BINS;
        const int b = tid - c * N_BINS;
        atomicAdd(&bins[tid], s_bins[0][c][b] + s_bins[1][c][b]
                            + s_bins[2][c][b] + s_bins[3][c][b]);
    }
}

__global__ void ece_final(const float* __restrict__ bins,
                          float* __restrict__ out, int n_rows)
{
    if (threadIdx.x == 0 && blockIdx.x == 0) {
        float ece = 0.f;
        for (int i = 0; i < N_BINS; ++i) {
            float c = bins[i];
            if (c > 0.f) {
                float gap = fabsf(bins[N_BINS + i] / c - bins[2 * N_BINS + i] / c);
                ece += gap * (c / (float)n_rows);
            }
        }
        out[0] = ece;
    }
}

extern "C" void kernel_launch(void* const* d_in, const int* in_sizes, int n_in,
                              void* d_out, int out_size, void* d_ws, size_t ws_size,
                              hipStream_t stream) {
    const float* probs    = (const float*)d_in[0];
    const int*   labels   = (const int*)d_in[1];
    const int*   is_logit = (const int*)d_in[2];
    float*       out      = (float*)d_out;
    float*       bins     = (float*)d_ws;
    const int n_rows = in_sizes[1];   // 2,000,000

    hipMemsetAsync(bins, 0, 3 * N_BINS * sizeof(float), stream);
    ece_main<<<BLOCKS, 256, 0, stream>>>(probs, labels, is_logit, bins, n_rows);
    ece_final<<<1, 64, 0, stream>>>(bins, out, n_rows);
}